// Round 4
// baseline (1626.972 us; speedup 1.0000x reference)
//
#include <hip/hip_runtime.h>
#include <math.h>

// Problem constants
#define K_CODES   1024
#define D_DIM     256
#define HW_SZ     1024          // 32*32
#define N_TOT     65536         // 64 * 1024
#define ND_TOT    16777216.0f   // N_TOT * D_DIM

// Output layout (float32, concatenated in reference return order)
#define O_ZQ    0
#define O_LOSS  16777216
#define O_IDX   16777217
#define O_CB    16842753
#define O_CS    17104897
#define O_DW    17105921

// ---------------------------------------------------------------------------
// Transpose codebook [K][D] -> CT [D][K] (scratch in z_q region; consumed by
// k_argmin before k_gather overwrites it)
__global__ void k_transpose(const float* __restrict__ cb, float* __restrict__ ct) {
    __shared__ float tile[32][33];
    int k0 = blockIdx.x * 32;
    int d0 = blockIdx.y * 32;
    int c = threadIdx.x & 31, r0 = threadIdx.x >> 5;
#pragma unroll
    for (int p = 0; p < 4; ++p) {
        int r = r0 + p * 8;
        tile[r][c] = cb[(k0 + r) * D_DIM + d0 + c];
    }
    __syncthreads();
#pragma unroll
    for (int p = 0; p < 4; ++p) {
        int r = r0 + p * 8;
        ct[(size_t)(d0 + r) * K_CODES + k0 + c] = tile[c][r];
    }
}

// ---------------------------------------------------------------------------
// Per-code squared norms, numpy-pairwise fp32 semantics (contract OFF:
// product rounded, then added — numpy materializes cb*cb first).
__global__ void k_cnorm(const float* __restrict__ cb, float* __restrict__ cn) {
#pragma clang fp contract(off)
    int k = blockIdx.x * 256 + threadIdx.x;            // grid = 4 blocks
    const float* row = cb + (size_t)k * D_DIM;
    float s1 = 0.f, s2 = 0.f;
#pragma unroll
    for (int blk = 0; blk < 2; ++blk) {
        const float* p = row + blk * 128;
        float r[8];
#pragma unroll
        for (int j = 0; j < 8; ++j) { float v = p[j]; r[j] = v * v; }
        for (int i = 8; i < 128; i += 8) {
#pragma unroll
            for (int j = 0; j < 8; ++j) { float v = p[i + j]; r[j] = r[j] + v * v; }
        }
        float s = ((r[0] + r[1]) + (r[2] + r[3])) + ((r[4] + r[5]) + (r[6] + r[7]));
        if (blk == 0) s1 = s; else s2 = s;
    }
    cn[k] = s1 + s2;
}

// ---------------------------------------------------------------------------
// Per-row squared norms, numpy-pairwise fp32 semantics (strided reads:
// consecutive lanes hit consecutive hw -> coalesced).
__global__ void k_zn(const float* __restrict__ ze, float* __restrict__ zn) {
#pragma clang fp contract(off)
    int n = blockIdx.x * 256 + threadIdx.x;            // grid = 256 blocks
    int b = n >> 10, hw = n & 1023;
    const float* p = ze + (size_t)b * (D_DIM * HW_SZ) + hw;
    float s1 = 0.f, s2 = 0.f;
#pragma unroll
    for (int blk = 0; blk < 2; ++blk) {
        const float* q = p + (size_t)(blk * 128) * HW_SZ;
        float r[8];
#pragma unroll
        for (int j = 0; j < 8; ++j) { float v = q[(size_t)j * HW_SZ]; r[j] = v * v; }
        for (int i = 8; i < 128; i += 8) {
#pragma unroll
            for (int j = 0; j < 8; ++j) {
                float v = q[(size_t)(i + j) * HW_SZ];
                r[j] = r[j] + v * v;
            }
        }
        float s = ((r[0] + r[1]) + (r[2] + r[3])) + ((r[4] + r[5]) + (r[6] + r[7]));
        if (blk == 0) s1 = s; else s2 = s;
    }
    zn[n] = s1 + s2;
}

// ---------------------------------------------------------------------------
// Main argmin kernel, np-fp32-replicated scores:
//   s = fl32( fl32(zn - 2*G) + cn ),  G = sequential fmaf over d (BLAS order)
// block = 64 n-rows x all K codes (8 chunks of 128); 4n x 8k per thread.
__global__ __launch_bounds__(256, 3)
void k_argmin(const float* __restrict__ ze, const float* __restrict__ ct,
              const float* __restrict__ cn, const float* __restrict__ znb,
              float* __restrict__ out_idx) {
    __shared__ __align__(16) float Zs[64][64];     // [d][n]
    __shared__ __align__(16) float Cs[64][132];    // [d][k], padded

    const int t  = threadIdx.x;
    const int tx = t & 15;       // k-group
    const int ty = t >> 4;       // n-group
    const int n0 = blockIdx.x * 64;
    const int b  = n0 >> 10;
    const int hw0 = n0 & 1023;
    const float* zb = ze + (size_t)b * (D_DIM * HW_SZ) + hw0;

    float znr[4];
#pragma unroll
    for (int j = 0; j < 4; ++j) znr[j] = znb[n0 + ty * 4 + j];

    float best[4];
    int   bidx[4];
#pragma unroll
    for (int j = 0; j < 4; ++j) { best[j] = INFINITY; bidx[j] = 0; }

    for (int kc = 0; kc < 8; ++kc) {
        float acc[4][8];
#pragma unroll
        for (int j = 0; j < 4; ++j)
#pragma unroll
            for (int i = 0; i < 8; ++i) acc[j][i] = 0.f;

        for (int dc = 0; dc < 4; ++dc) {
            __syncthreads();
#pragma unroll
            for (int r = 0; r < 4; ++r) {              // stage Z: 64d x 64n
                int idx4 = r * 256 + t;
                int dd = idx4 >> 4, nn4 = (idx4 & 15) * 4;
                float4 v = *(const float4*)(zb + (size_t)(dc * 64 + dd) * HW_SZ + nn4);
                *(float4*)&Zs[dd][nn4] = v;
            }
#pragma unroll
            for (int r = 0; r < 8; ++r) {              // stage C: 64d x 128k
                int idx4 = r * 256 + t;
                int dd = idx4 >> 5, kk4 = (idx4 & 31) * 4;
                float4 v = *(const float4*)(ct + (size_t)(dc * 64 + dd) * K_CODES + kc * 128 + kk4);
                *(float4*)&Cs[dd][kk4] = v;
            }
            __syncthreads();
#pragma unroll 2
            for (int d = 0; d < 64; ++d) {
                float4 z4 = *(const float4*)&Zs[d][ty * 4];
                float4 c0 = *(const float4*)&Cs[d][tx * 4];
                float4 c1 = *(const float4*)&Cs[d][64 + tx * 4];
                float zz[4] = { z4.x, z4.y, z4.z, z4.w };
                float cc[8] = { c0.x, c0.y, c0.z, c0.w, c1.x, c1.y, c1.z, c1.w };
#pragma unroll
                for (int j = 0; j < 4; ++j)
#pragma unroll
                    for (int i = 0; i < 8; ++i)
                        acc[j][i] = fmaf(zz[j], cc[i], acc[j][i]);
            }
        }
        // fold: s = fl32(fl32(zn - 2*acc) + cn); running argmin
        // (2*acc exact, so contraction of the subtract is value-identical)
#pragma unroll
        for (int i = 0; i < 8; ++i) {
            int k = kc * 128 + (i >> 2) * 64 + tx * 4 + (i & 3);
            float cnk = cn[k];
#pragma unroll
            for (int j = 0; j < 4; ++j) {
                float tt = znr[j] - 2.0f * acc[j][i];
                float s  = tt + cnk;
                if (s < best[j]) { best[j] = s; bidx[j] = k; }
            }
        }
    }

    // cross-thread (tx) reduction via LDS reuse; lexicographic (v, idx)
    __syncthreads();
    float* rv = &Zs[0][0];
    int*   ri = (int*)&Cs[0][0];
#pragma unroll
    for (int j = 0; j < 4; ++j) {
        int n = ty * 4 + j;
        rv[n * 17 + tx] = best[j];
        ri[n * 17 + tx] = bidx[j];
    }
    __syncthreads();
    if (t < 64) {
        float bv = INFINITY; int bi = 0;
        for (int x = 0; x < 16; ++x) {
            float v = rv[t * 17 + x];
            int  id = ri[t * 17 + x];
            if (v < bv || (v == bv && id < bi)) { bv = v; bi = id; }
        }
        out_idx[n0 + t] = (float)bi;
    }
}

// ---------------------------------------------------------------------------
// Gather z_q, straight-through out0, loss partials, counts + dw scatter-add.
__global__ __launch_bounds__(256)
void k_gather(const float* __restrict__ ze, const float* __restrict__ cb,
              const float* __restrict__ idxf, float* __restrict__ out0,
              float* __restrict__ dwraw, float* __restrict__ counts,
              float* __restrict__ lossacc) {
    int n = blockIdx.x * 256 + threadIdx.x;
    int b = n >> 10, hw = n & 1023;
    size_t base = (size_t)b * (D_DIM * HW_SZ) + hw;
    int idx = (int)idxf[n];
    const float* crow = cb + (size_t)idx * D_DIM;
    float* drow = dwraw + (size_t)idx * D_DIM;
    atomicAdd(counts + idx, 1.0f);
    float ls = 0.f;
    for (int d = 0; d < D_DIM; ++d) {
        float z = ze[base + (size_t)d * HW_SZ];
        float c = crow[d];
        float diff = c - z;
        out0[base + (size_t)d * HW_SZ] = z + diff;
        ls += diff * diff;
        atomicAdd(drow + d, z);
    }
    __shared__ float red[4];
#pragma unroll
    for (int off = 32; off > 0; off >>= 1) ls += __shfl_down(ls, off, 64);
    if ((threadIdx.x & 63) == 0) red[threadIdx.x >> 6] = ls;
    __syncthreads();
    if (threadIdx.x == 0) atomicAdd(lossacc, red[0] + red[1] + red[2] + red[3]);
}

// ---------------------------------------------------------------------------
__global__ __launch_bounds__(1024)
void k_ema_cs(const float* __restrict__ ema_cs, const float* __restrict__ counts,
              float* __restrict__ out_cs, float* __restrict__ smoothed,
              const float* __restrict__ lossacc, float* __restrict__ out_loss) {
    __shared__ float red[1024];
    int k = threadIdx.x;
    float cs_new = fmaf(0.99f, ema_cs[k], 0.01f * counts[k]);
    red[k] = cs_new;
    __syncthreads();
    for (int off = 512; off > 0; off >>= 1) {
        if (k < off) red[k] += red[k + off];
        __syncthreads();
    }
    float ntot = red[0];
    out_cs[k] = cs_new;
    smoothed[k] = (cs_new + 1e-5f) / (ntot + 0.01024f) * ntot;
    if (k == 0) out_loss[0] = 0.5f * lossacc[0] / ND_TOT;
}

// ---------------------------------------------------------------------------
__global__ __launch_bounds__(256)
void k_ema_dw(const float* __restrict__ ema_dw, const float* __restrict__ smoothed,
              float* __restrict__ out_dw, float* __restrict__ out_cb) {
    int k = blockIdx.x, d = threadIdx.x;
    size_t o = (size_t)k * D_DIM + d;
    float nd = fmaf(0.99f, ema_dw[o], 0.01f * out_dw[o]);
    out_dw[o] = nd;
    out_cb[o] = nd / smoothed[k];
}

// ---------------------------------------------------------------------------
extern "C" void kernel_launch(void* const* d_in, const int* in_sizes, int n_in,
                              void* d_out, int out_size, void* d_ws, size_t ws_size,
                              hipStream_t stream) {
    const float* ze     = (const float*)d_in[0];  // [64,256,32,32]
    const float* cb     = (const float*)d_in[1];  // [1024,256]
    const float* emacs  = (const float*)d_in[2];  // [1024]
    const float* emadw  = (const float*)d_in[3];  // [1024,256]
    float* out = (float*)d_out;
    float* ws  = (float*)d_ws;

    // scratch in z_q region (consumed by k_argmin, overwritten by k_gather)
    float* CT = out;                      // 262144 floats: CB^T [D][K]
    // zn floats in the new_cb region (overwritten last by k_ema_dw)
    float* ZN = out + O_CB;               // 65536 floats
    // d_ws scratch
    float* counts   = ws;                 // 1024
    float* lossacc  = ws + 1024;          // 1
    float* smoothed = ws + 1088;          // 1024
    float* CN       = ws + 2112;          // 1024

    hipMemsetAsync(ws, 0, 1025 * sizeof(float), stream);
    hipMemsetAsync(out + O_DW, 0, (size_t)K_CODES * D_DIM * sizeof(float), stream);

    k_transpose<<<dim3(32, 8), 256, 0, stream>>>(cb, CT);
    k_cnorm<<<4, 256, 0, stream>>>(cb, CN);
    k_zn<<<256, 256, 0, stream>>>(ze, ZN);
    k_argmin<<<N_TOT / 64, 256, 0, stream>>>(ze, CT, CN, ZN, out + O_IDX);
    k_gather<<<N_TOT / 256, 256, 0, stream>>>(ze, cb, out + O_IDX, out + O_ZQ,
                                              out + O_DW, counts, lossacc);
    k_ema_cs<<<1, 1024, 0, stream>>>(emacs, counts, out + O_CS, smoothed,
                                     lossacc, out + O_LOSS);
    k_ema_dw<<<K_CODES, 256, 0, stream>>>(emadw, smoothed, out + O_DW, out + O_CB);
}

// Round 5
// 821.483 us; speedup vs baseline: 1.9805x; 1.9805x over previous
//
#include <hip/hip_runtime.h>
#include <math.h>

// Problem constants
#define K_CODES   1024
#define D_DIM     256
#define HW_SZ     1024          // 32*32
#define N_TOT     65536         // 64 * 1024
#define ND_TOT    16777216.0f   // N_TOT * D_DIM

// Output layout (float32, concatenated in reference return order)
#define O_ZQ    0
#define O_LOSS  16777216
#define O_IDX   16777217
#define O_CB    16842753
#define O_CS    17104897
#define O_DW    17105921

// ---------------------------------------------------------------------------
// Transpose codebook [K][D] -> CT [D][K].  CT lives at the FRONT of the z_q
// output region (16B-aligned); consumed by k_argmin, then overwritten by k_zt.
__global__ void k_transpose(const float* __restrict__ cb, float* __restrict__ ct) {
    __shared__ float tile[32][33];
    int k0 = blockIdx.x * 32;
    int d0 = blockIdx.y * 32;
    int c = threadIdx.x & 31, r0 = threadIdx.x >> 5;
#pragma unroll
    for (int p = 0; p < 4; ++p) {
        int r = r0 + p * 8;
        tile[r][c] = cb[(k0 + r) * D_DIM + d0 + c];
    }
    __syncthreads();
#pragma unroll
    for (int p = 0; p < 4; ++p) {
        int r = r0 + p * 8;
        ct[(size_t)(d0 + r) * K_CODES + k0 + c] = tile[c][r];
    }
}

// ---------------------------------------------------------------------------
// Per-code squared norms, numpy-pairwise fp32 semantics (contract OFF).
__global__ void k_cnorm(const float* __restrict__ cb, float* __restrict__ cn) {
#pragma clang fp contract(off)
    int k = blockIdx.x * 256 + threadIdx.x;            // grid = 4 blocks
    const float* row = cb + (size_t)k * D_DIM;
    float s1 = 0.f, s2 = 0.f;
#pragma unroll
    for (int blk = 0; blk < 2; ++blk) {
        const float* p = row + blk * 128;
        float r[8];
#pragma unroll
        for (int j = 0; j < 8; ++j) { float v = p[j]; r[j] = v * v; }
        for (int i = 8; i < 128; i += 8) {
#pragma unroll
            for (int j = 0; j < 8; ++j) { float v = p[i + j]; r[j] = r[j] + v * v; }
        }
        float s = ((r[0] + r[1]) + (r[2] + r[3])) + ((r[4] + r[5]) + (r[6] + r[7]));
        if (blk == 0) s1 = s; else s2 = s;
    }
    cn[k] = s1 + s2;
}

// ---------------------------------------------------------------------------
// Per-row squared norms, numpy-pairwise fp32 semantics. Written into the
// O_IDX region; k_argmin later overwrites it in-place (block-local).
__global__ void k_zn(const float* __restrict__ ze, float* __restrict__ zn) {
#pragma clang fp contract(off)
    int n = blockIdx.x * 256 + threadIdx.x;            // grid = 256 blocks
    int b = n >> 10, hw = n & 1023;
    const float* p = ze + (size_t)b * (D_DIM * HW_SZ) + hw;
    float s1 = 0.f, s2 = 0.f;
#pragma unroll
    for (int blk = 0; blk < 2; ++blk) {
        const float* q = p + (size_t)(blk * 128) * HW_SZ;
        float r[8];
#pragma unroll
        for (int j = 0; j < 8; ++j) { float v = q[(size_t)j * HW_SZ]; r[j] = v * v; }
        for (int i = 8; i < 128; i += 8) {
#pragma unroll
            for (int j = 0; j < 8; ++j) {
                float v = q[(size_t)(i + j) * HW_SZ];
                r[j] = r[j] + v * v;
            }
        }
        float s = ((r[0] + r[1]) + (r[2] + r[3])) + ((r[4] + r[5]) + (r[6] + r[7]));
        if (blk == 0) s1 = s; else s2 = s;
    }
    zn[n] = s1 + s2;
}

// ---------------------------------------------------------------------------
// Main argmin kernel (math unchanged from round-4 passing version):
//   s = fl32( fl32(zn - 2*G) + cn ),  G = sequential fmaf over d
// Adds fused counts histogram (one atomic per row, amortized over ~600us).
__global__ __launch_bounds__(256, 3)
void k_argmin(const float* __restrict__ ze, const float* __restrict__ ct,
              const float* __restrict__ cn, const float* __restrict__ znb,
              float* __restrict__ out_idx, float* __restrict__ counts) {
    __shared__ __align__(16) float Zs[64][64];     // [d][n]
    __shared__ __align__(16) float Cs[64][132];    // [d][k], padded

    const int t  = threadIdx.x;
    const int tx = t & 15;       // k-group
    const int ty = t >> 4;       // n-group
    const int n0 = blockIdx.x * 64;
    const int b  = n0 >> 10;
    const int hw0 = n0 & 1023;
    const float* zb = ze + (size_t)b * (D_DIM * HW_SZ) + hw0;

    float znr[4];
#pragma unroll
    for (int j = 0; j < 4; ++j) znr[j] = znb[n0 + ty * 4 + j];

    float best[4];
    int   bidx[4];
#pragma unroll
    for (int j = 0; j < 4; ++j) { best[j] = INFINITY; bidx[j] = 0; }

    for (int kc = 0; kc < 8; ++kc) {
        float acc[4][8];
#pragma unroll
        for (int j = 0; j < 4; ++j)
#pragma unroll
            for (int i = 0; i < 8; ++i) acc[j][i] = 0.f;

        for (int dc = 0; dc < 4; ++dc) {
            __syncthreads();
#pragma unroll
            for (int r = 0; r < 4; ++r) {              // stage Z: 64d x 64n
                int idx4 = r * 256 + t;
                int dd = idx4 >> 4, nn4 = (idx4 & 15) * 4;
                float4 v = *(const float4*)(zb + (size_t)(dc * 64 + dd) * HW_SZ + nn4);
                *(float4*)&Zs[dd][nn4] = v;
            }
#pragma unroll
            for (int r = 0; r < 8; ++r) {              // stage C: 64d x 128k
                int idx4 = r * 256 + t;
                int dd = idx4 >> 5, kk4 = (idx4 & 31) * 4;
                float4 v = *(const float4*)(ct + (size_t)(dc * 64 + dd) * K_CODES + kc * 128 + kk4);
                *(float4*)&Cs[dd][kk4] = v;
            }
            __syncthreads();
#pragma unroll 2
            for (int d = 0; d < 64; ++d) {
                float4 z4 = *(const float4*)&Zs[d][ty * 4];
                float4 c0 = *(const float4*)&Cs[d][tx * 4];
                float4 c1 = *(const float4*)&Cs[d][64 + tx * 4];
                float zz[4] = { z4.x, z4.y, z4.z, z4.w };
                float cc[8] = { c0.x, c0.y, c0.z, c0.w, c1.x, c1.y, c1.z, c1.w };
#pragma unroll
                for (int j = 0; j < 4; ++j)
#pragma unroll
                    for (int i = 0; i < 8; ++i)
                        acc[j][i] = fmaf(zz[j], cc[i], acc[j][i]);
            }
        }
#pragma unroll
        for (int i = 0; i < 8; ++i) {
            int k = kc * 128 + (i >> 2) * 64 + tx * 4 + (i & 3);
            float cnk = cn[k];
#pragma unroll
            for (int j = 0; j < 4; ++j) {
                float tt = znr[j] - 2.0f * acc[j][i];
                float s  = tt + cnk;
                if (s < best[j]) { best[j] = s; bidx[j] = k; }
            }
        }
    }

    __syncthreads();
    float* rv = &Zs[0][0];
    int*   ri = (int*)&Cs[0][0];
#pragma unroll
    for (int j = 0; j < 4; ++j) {
        int n = ty * 4 + j;
        rv[n * 17 + tx] = best[j];
        ri[n * 17 + tx] = bidx[j];
    }
    __syncthreads();
    if (t < 64) {
        float bv = INFINITY; int bi = 0;
        for (int x = 0; x < 16; ++x) {
            float v = rv[t * 17 + x];
            int  id = ri[t * 17 + x];
            if (v < bv || (v == bv && id < bi)) { bv = v; bi = id; }
        }
        out_idx[n0 + t] = (float)bi;
        atomicAdd(counts + bi, 1.0f);
    }
}

// ---------------------------------------------------------------------------
// Transpose z_e [64][256][1024] -> zflat [65536][256] (into O_ZQ region,
// overwriting the now-dead CT).
__global__ __launch_bounds__(256)
void k_zt(const float* __restrict__ ze, float* __restrict__ zflat) {
    __shared__ float tile[64][65];
    const int t = threadIdx.x;
    const int hw0 = blockIdx.x * 64;
    const int d0  = blockIdx.y * 64;
    const int b   = blockIdx.z;
    const size_t base_in = (size_t)b * (D_DIM * HW_SZ);
#pragma unroll
    for (int p = 0; p < 4; ++p) {
        int dd = p * 16 + (t >> 4);
        int c4 = (t & 15) * 4;
        float4 v = *(const float4*)(ze + base_in + (size_t)(d0 + dd) * HW_SZ + hw0 + c4);
        tile[dd][c4 + 0] = v.x;
        tile[dd][c4 + 1] = v.y;
        tile[dd][c4 + 2] = v.z;
        tile[dd][c4 + 3] = v.w;
    }
    __syncthreads();
#pragma unroll
    for (int p = 0; p < 4; ++p) {
        int hh  = p * 16 + (t >> 4);
        int dc4 = (t & 15) * 4;
        float4 v = { tile[dc4 + 0][hh], tile[dc4 + 1][hh],
                     tile[dc4 + 2][hh], tile[dc4 + 3][hh] };
        *(float4*)(zflat + (size_t)(b * HW_SZ + hw0 + hh) * D_DIM + d0 + dc4) = v;
    }
}

// ---------------------------------------------------------------------------
// EMA cluster size + smoothed (loss finalize moved to k_zq).
__global__ __launch_bounds__(1024)
void k_ema_cs(const float* __restrict__ ema_cs, const float* __restrict__ counts,
              float* __restrict__ out_cs, float* __restrict__ smoothed) {
    __shared__ float red[1024];
    int k = threadIdx.x;
    float cs_new = fmaf(0.99f, ema_cs[k], 0.01f * counts[k]);
    red[k] = cs_new;
    __syncthreads();
    for (int off = 512; off > 0; off >>= 1) {
        if (k < off) red[k] += red[k + off];
        __syncthreads();
    }
    float ntot = red[0];
    out_cs[k] = cs_new;
    smoothed[k] = (cs_new + 1e-5f) / (ntot + 0.01024f) * ntot;
}

// ---------------------------------------------------------------------------
// Per-code segment sum (replaces 16.7M global atomics): one block per code.
// Scans idx (L2-resident), compacts matching rows into an LDS queue, sums
// rows coalesced from zflat. Fuses commit-loss partials and the dw EMA +
// codebook write.
__global__ __launch_bounds__(256)
void k_dwsum(const float* __restrict__ idxf, const float* __restrict__ zflat,
             const float* __restrict__ cb, const float* __restrict__ ema_dw,
             const float* __restrict__ smoothed, float* __restrict__ out_dw,
             float* __restrict__ out_cb, float* __restrict__ lossacc) {
    __shared__ int queue[1024];
    __shared__ int qn;
    __shared__ float lred[4];

    const int k = blockIdx.x;
    const int t = threadIdx.x;
    const float fk = (float)k;
    const float ck = cb[(size_t)k * D_DIM + t];

    float acc = 0.f;
    float ls  = 0.f;

    for (int chunk = 0; chunk < 64; ++chunk) {
        if (t == 0) qn = 0;
        __syncthreads();
#pragma unroll
        for (int j = 0; j < 4; ++j) {
            int n = chunk * 1024 + j * 256 + t;        // coalesced idx read
            if (idxf[n] == fk) {
                int p = atomicAdd(&qn, 1);
                queue[p] = n;
            }
        }
        __syncthreads();
        int m = qn;
        for (int i = 0; i < m; ++i) {
            int n = queue[i];
            float z = zflat[(size_t)n * D_DIM + t];    // coalesced row read
            acc += z;
            float df = ck - z;                         // same rounding as ref
            ls += df * df;
        }
    }

    // dw EMA + codebook write
    size_t o = (size_t)k * D_DIM + t;
    float nd = fmaf(0.99f, ema_dw[o], 0.01f * acc);
    out_dw[o] = nd;
    out_cb[o] = nd / smoothed[k];

    // block-reduce loss partials -> one atomic per block
#pragma unroll
    for (int off = 32; off > 0; off >>= 1) ls += __shfl_down(ls, off, 64);
    if ((t & 63) == 0) lred[t >> 6] = ls;
    __syncthreads();
    if (t == 0) atomicAdd(lossacc, lred[0] + lred[1] + lred[2] + lred[3]);
}

// ---------------------------------------------------------------------------
// Straight-through z_q writer: pure float4 stream + L2 codebook gather.
// Also finalizes the loss (lossacc complete from k_dwsum, stream-ordered).
__global__ __launch_bounds__(256)
void k_zq(const float* __restrict__ ze, const float* __restrict__ cb,
          const float* __restrict__ idxf, float* __restrict__ out0,
          const float* __restrict__ lossacc, float* __restrict__ out_loss) {
    const int t = threadIdx.x;
    int g   = blockIdx.x * 64 + (t & 63);   // hw4-group id in [0, 16384)
    int b   = g >> 8;
    int hwl = (g & 255) * 4;
    int dg  = t >> 6;                        // d-quarter (0..3)
    const size_t base = (size_t)b * (D_DIM * HW_SZ) + hwl;

    int i0 = (int)idxf[b * HW_SZ + hwl + 0];
    int i1 = (int)idxf[b * HW_SZ + hwl + 1];
    int i2 = (int)idxf[b * HW_SZ + hwl + 2];
    int i3 = (int)idxf[b * HW_SZ + hwl + 3];
    const float* c0 = cb + (size_t)i0 * D_DIM;
    const float* c1 = cb + (size_t)i1 * D_DIM;
    const float* c2 = cb + (size_t)i2 * D_DIM;
    const float* c3 = cb + (size_t)i3 * D_DIM;

#pragma unroll 2
    for (int i = 0; i < 64; ++i) {
        int d = dg * 64 + i;
        size_t o = base + (size_t)d * HW_SZ;
        float4 z = *(const float4*)(ze + o);
        float4 r;
        r.x = z.x + (c0[d] - z.x);
        r.y = z.y + (c1[d] - z.y);
        r.z = z.z + (c2[d] - z.z);
        r.w = z.w + (c3[d] - z.w);
        *(float4*)(out0 + o) = r;
    }

    if (blockIdx.x == 0 && t == 0)
        out_loss[0] = 0.5f * lossacc[0] / ND_TOT;
}

// ---------------------------------------------------------------------------
extern "C" void kernel_launch(void* const* d_in, const int* in_sizes, int n_in,
                              void* d_out, int out_size, void* d_ws, size_t ws_size,
                              hipStream_t stream) {
    const float* ze     = (const float*)d_in[0];  // [64,256,32,32]
    const float* cb     = (const float*)d_in[1];  // [1024,256]
    const float* emacs  = (const float*)d_in[2];  // [1024]
    const float* emadw  = (const float*)d_in[3];  // [1024,256]
    float* out = (float*)d_out;
    float* ws  = (float*)d_ws;

    // Scratch choreography (stream-ordered reuse of d_out):
    //   CT (262144 fl) at out+0        : written by k_transpose, read by k_argmin,
    //                                    then overwritten by k_zt's zflat.
    //   zflat (16.7M)  at out+0        : written by k_zt, read by k_dwsum,
    //                                    then overwritten by k_zq (final z_q).
    //   ZN (65536)     at out+O_IDX    : written by k_zn, overwritten in-place
    //                                    by k_argmin's indices (block-local).
    float* CT    = out;
    float* ZFLAT = out;
    float* ZN    = out + O_IDX;
    // d_ws scratch (~12.5 KB, proven size)
    float* counts   = ws;                 // 1024
    float* lossacc  = ws + 1024;          // 1
    float* smoothed = ws + 1088;          // 1024
    float* CN       = ws + 2112;          // 1024

    hipMemsetAsync(ws, 0, 1025 * sizeof(float), stream);

    k_transpose<<<dim3(32, 8), 256, 0, stream>>>(cb, CT);
    k_cnorm<<<4, 256, 0, stream>>>(cb, CN);
    k_zn<<<256, 256, 0, stream>>>(ze, ZN);
    k_argmin<<<N_TOT / 64, 256, 0, stream>>>(ze, CT, CN, ZN, out + O_IDX, counts);
    k_zt<<<dim3(16, 4, 64), 256, 0, stream>>>(ze, ZFLAT);
    k_ema_cs<<<1, 1024, 0, stream>>>(emacs, counts, out + O_CS, smoothed);
    k_dwsum<<<K_CODES, 256, 0, stream>>>(out + O_IDX, ZFLAT, cb, emadw, smoothed,
                                         out + O_DW, out + O_CB, lossacc);
    k_zq<<<256, 256, 0, stream>>>(ze, cb, out + O_IDX, out + O_ZQ,
                                  lossacc, out + O_LOSS);
}

// Round 6
// 700.932 us; speedup vs baseline: 2.3212x; 1.1720x over previous
//
#include <hip/hip_runtime.h>
#include <math.h>

// Problem constants
#define K_CODES   1024
#define D_DIM     256
#define HW_SZ     1024          // 32*32
#define N_TOT     65536         // 64 * 1024
#define ND_TOT    16777216.0f   // N_TOT * D_DIM

// Output layout (float32, concatenated in reference return order)
#define O_ZQ    0
#define O_LOSS  16777216
#define O_IDX   16777217
#define O_CB    16842753
#define O_CS    17104897
#define O_DW    17105921

typedef float f2 __attribute__((ext_vector_type(2)));

// ---------------------------------------------------------------------------
// Transpose codebook [K][D] -> CT [D][K].  CT lives at the FRONT of the z_q
// output region (16B-aligned); consumed by k_argmin, then overwritten by k_zt.
__global__ void k_transpose(const float* __restrict__ cb, float* __restrict__ ct) {
    __shared__ float tile[32][33];
    int k0 = blockIdx.x * 32;
    int d0 = blockIdx.y * 32;
    int c = threadIdx.x & 31, r0 = threadIdx.x >> 5;
#pragma unroll
    for (int p = 0; p < 4; ++p) {
        int r = r0 + p * 8;
        tile[r][c] = cb[(k0 + r) * D_DIM + d0 + c];
    }
    __syncthreads();
#pragma unroll
    for (int p = 0; p < 4; ++p) {
        int r = r0 + p * 8;
        ct[(size_t)(d0 + r) * K_CODES + k0 + c] = tile[c][r];
    }
}

// ---------------------------------------------------------------------------
// Per-code squared norms, numpy-pairwise fp32 semantics (contract OFF).
__global__ void k_cnorm(const float* __restrict__ cb, float* __restrict__ cn) {
#pragma clang fp contract(off)
    int k = blockIdx.x * 256 + threadIdx.x;            // grid = 4 blocks
    const float* row = cb + (size_t)k * D_DIM;
    float s1 = 0.f, s2 = 0.f;
#pragma unroll
    for (int blk = 0; blk < 2; ++blk) {
        const float* p = row + blk * 128;
        float r[8];
#pragma unroll
        for (int j = 0; j < 8; ++j) { float v = p[j]; r[j] = v * v; }
        for (int i = 8; i < 128; i += 8) {
#pragma unroll
            for (int j = 0; j < 8; ++j) { float v = p[i + j]; r[j] = r[j] + v * v; }
        }
        float s = ((r[0] + r[1]) + (r[2] + r[3])) + ((r[4] + r[5]) + (r[6] + r[7]));
        if (blk == 0) s1 = s; else s2 = s;
    }
    cn[k] = s1 + s2;
}

// ---------------------------------------------------------------------------
// Per-row squared norms, numpy-pairwise fp32 semantics. Written into the
// O_IDX region; k_argmin later overwrites it in-place (block-local).
__global__ void k_zn(const float* __restrict__ ze, float* __restrict__ zn) {
#pragma clang fp contract(off)
    int n = blockIdx.x * 256 + threadIdx.x;            // grid = 256 blocks
    int b = n >> 10, hw = n & 1023;
    const float* p = ze + (size_t)b * (D_DIM * HW_SZ) + hw;
    float s1 = 0.f, s2 = 0.f;
#pragma unroll
    for (int blk = 0; blk < 2; ++blk) {
        const float* q = p + (size_t)(blk * 128) * HW_SZ;
        float r[8];
#pragma unroll
        for (int j = 0; j < 8; ++j) { float v = q[(size_t)j * HW_SZ]; r[j] = v * v; }
        for (int i = 8; i < 128; i += 8) {
#pragma unroll
            for (int j = 0; j < 8; ++j) {
                float v = q[(size_t)(i + j) * HW_SZ];
                r[j] = r[j] + v * v;
            }
        }
        float s = ((r[0] + r[1]) + (r[2] + r[3])) + ((r[4] + r[5]) + (r[6] + r[7]));
        if (blk == 0) s1 = s; else s2 = s;
    }
    zn[n] = s1 + s2;
}

// ---------------------------------------------------------------------------
// Main argmin kernel. Scores bit-identical to the passing round-4 version:
//   s = fl32( fl32(zn - 2*G) + cn ),  G = sequential fmaf over ascending d.
// New structure: 8n x 16k micro-tile (0.75 B LDS / FMA vs 1.5 before),
// 128n x 256k block tile, dc=32, global_load_lds width-16 staging,
// float2-packed FMA (per-component order unchanged -> bit-exact).
__global__ __launch_bounds__(256, 2)
void k_argmin(const float* __restrict__ ze, const float* __restrict__ ct,
              const float* __restrict__ cn, const float* __restrict__ znb,
              float* __restrict__ out_idx, float* __restrict__ counts) {
    __shared__ __align__(16) float Zs[32][128];    // [d][n], rows contiguous
    __shared__ __align__(16) float Cs[32][260];    // [d][k], +4 pad per row

    const int t  = threadIdx.x;
    const int tx = t & 15;       // k-group (16 -> 16*16k = 256k)
    const int ty = t >> 4;       // n-group (16 -> 16*8n = 128n)
    const int n0 = blockIdx.x * 128;
    const int b  = n0 >> 10;
    const int hw0 = n0 & 1023;
    const float* zb = ze + (size_t)b * (D_DIM * HW_SZ) + hw0;

    float znr[8];
#pragma unroll
    for (int j = 0; j < 8; ++j) znr[j] = znb[n0 + ty * 8 + j];

    float best[8];
    int   bidx[8];
#pragma unroll
    for (int j = 0; j < 8; ++j) { best[j] = INFINITY; bidx[j] = 0; }

    for (int kc = 0; kc < 4; ++kc) {
        f2 acc2[8][8];
#pragma unroll
        for (int j = 0; j < 8; ++j)
#pragma unroll
            for (int i = 0; i < 8; ++i) acc2[j][i] = (f2)0.f;

        for (int dc = 0; dc < 8; ++dc) {
            __syncthreads();   // previous phase's LDS reads done before overwrite
            // stage Z: 32d x 128n via global_load_lds (LDS dest = idx4*16,
            // rows contiguous at stride 128 -> wave-uniform base + lane*16)
#pragma unroll
            for (int r = 0; r < 4; ++r) {
                int idx4 = r * 256 + t;
                int dd = idx4 >> 5, nn4 = (idx4 & 31) * 4;
                const float* g = zb + (size_t)(dc * 32 + dd) * HW_SZ + nn4;
                char* l = (char*)&Zs[0][0] + (size_t)(r * 256 + (t & ~63)) * 16;
                __builtin_amdgcn_global_load_lds(
                    (const __attribute__((address_space(1))) void*)g,
                    (__attribute__((address_space(3))) void*)l, 16, 0, 0);
            }
            // stage C: 32d x 256k; each wave fills exactly one 256-float row,
            // so the +4 row pad is never crossed within an instruction.
#pragma unroll
            for (int r = 0; r < 8; ++r) {
                int idx4 = r * 256 + t;
                int dd = idx4 >> 6, kk4 = (idx4 & 63) * 4;
                const float* g = ct + (size_t)(dc * 32 + dd) * K_CODES + kc * 256 + kk4;
                char* l = (char*)&Cs[0][0] + (size_t)dd * (260 * 4);
                __builtin_amdgcn_global_load_lds(
                    (const __attribute__((address_space(1))) void*)g,
                    (__attribute__((address_space(3))) void*)l, 16, 0, 0);
            }
            __syncthreads();
#pragma unroll 2
            for (int d = 0; d < 32; ++d) {
                float4 za  = *(const float4*)&Zs[d][ty * 8];
                float4 zb4 = *(const float4*)&Zs[d][ty * 8 + 4];
                float4 ca  = *(const float4*)&Cs[d][tx * 4];
                float4 cb4 = *(const float4*)&Cs[d][64 + tx * 4];
                float4 cc4 = *(const float4*)&Cs[d][128 + tx * 4];
                float4 cd4 = *(const float4*)&Cs[d][192 + tx * 4];
                float zzs[8] = { za.x, za.y, za.z, za.w, zb4.x, zb4.y, zb4.z, zb4.w };
                f2 cc2[8] = { { ca.x,  ca.y  }, { ca.z,  ca.w  },
                              { cb4.x, cb4.y }, { cb4.z, cb4.w },
                              { cc4.x, cc4.y }, { cc4.z, cc4.w },
                              { cd4.x, cd4.y }, { cd4.z, cd4.w } };
#pragma unroll
                for (int j = 0; j < 8; ++j) {
                    f2 zj = { zzs[j], zzs[j] };
#pragma unroll
                    for (int i = 0; i < 8; ++i)
                        acc2[j][i] = __builtin_elementwise_fma(zj, cc2[i], acc2[j][i]);
                }
            }
        }
        // fold: s = fl32(fl32(zn - 2*acc) + cn); k ascending per thread
#pragma unroll
        for (int q = 0; q < 4; ++q)
#pragma unroll
            for (int l = 0; l < 4; ++l) {
                int k = kc * 256 + q * 64 + tx * 4 + l;
                float cnk = cn[k];
                int i2 = q * 2 + (l >> 1);
#pragma unroll
                for (int j = 0; j < 8; ++j) {
                    float a = (l & 1) ? acc2[j][i2].y : acc2[j][i2].x;
                    float tt = znr[j] - 2.0f * a;
                    float s  = tt + cnk;
                    if (s < best[j]) { best[j] = s; bidx[j] = k; }
                }
            }
    }

    // cross-thread (tx) reduction via LDS reuse; lexicographic (v, idx)
    __syncthreads();
    float* rv = &Zs[0][0];          // 128*17 floats = 8704 B <= 16 KB
    int*   ri = (int*)&Cs[0][0];
#pragma unroll
    for (int j = 0; j < 8; ++j) {
        int n = ty * 8 + j;
        rv[n * 17 + tx] = best[j];
        ri[n * 17 + tx] = bidx[j];
    }
    __syncthreads();
    if (t < 128) {
        float bv = INFINITY; int bi = 0;
        for (int x = 0; x < 16; ++x) {
            float v = rv[t * 17 + x];
            int  id = ri[t * 17 + x];
            if (v < bv || (v == bv && id < bi)) { bv = v; bi = id; }
        }
        out_idx[n0 + t] = (float)bi;
        atomicAdd(counts + bi, 1.0f);
    }
}

// ---------------------------------------------------------------------------
// Transpose z_e [64][256][1024] -> zflat [65536][256] (into O_ZQ region,
// overwriting the now-dead CT).
__global__ __launch_bounds__(256)
void k_zt(const float* __restrict__ ze, float* __restrict__ zflat) {
    __shared__ float tile[64][65];
    const int t = threadIdx.x;
    const int hw0 = blockIdx.x * 64;
    const int d0  = blockIdx.y * 64;
    const int b   = blockIdx.z;
    const size_t base_in = (size_t)b * (D_DIM * HW_SZ);
#pragma unroll
    for (int p = 0; p < 4; ++p) {
        int dd = p * 16 + (t >> 4);
        int c4 = (t & 15) * 4;
        float4 v = *(const float4*)(ze + base_in + (size_t)(d0 + dd) * HW_SZ + hw0 + c4);
        tile[dd][c4 + 0] = v.x;
        tile[dd][c4 + 1] = v.y;
        tile[dd][c4 + 2] = v.z;
        tile[dd][c4 + 3] = v.w;
    }
    __syncthreads();
#pragma unroll
    for (int p = 0; p < 4; ++p) {
        int hh  = p * 16 + (t >> 4);
        int dc4 = (t & 15) * 4;
        float4 v = { tile[dc4 + 0][hh], tile[dc4 + 1][hh],
                     tile[dc4 + 2][hh], tile[dc4 + 3][hh] };
        *(float4*)(zflat + (size_t)(b * HW_SZ + hw0 + hh) * D_DIM + d0 + dc4) = v;
    }
}

// ---------------------------------------------------------------------------
// EMA cluster size + smoothed (loss finalize moved to k_zq).
__global__ __launch_bounds__(1024)
void k_ema_cs(const float* __restrict__ ema_cs, const float* __restrict__ counts,
              float* __restrict__ out_cs, float* __restrict__ smoothed) {
    __shared__ float red[1024];
    int k = threadIdx.x;
    float cs_new = fmaf(0.99f, ema_cs[k], 0.01f * counts[k]);
    red[k] = cs_new;
    __syncthreads();
    for (int off = 512; off > 0; off >>= 1) {
        if (k < off) red[k] += red[k + off];
        __syncthreads();
    }
    float ntot = red[0];
    out_cs[k] = cs_new;
    smoothed[k] = (cs_new + 1e-5f) / (ntot + 0.01024f) * ntot;
}

// ---------------------------------------------------------------------------
// Per-code segment sum: one block per code; compact matching rows into an LDS
// queue, sum rows coalesced from zflat. Fuses loss partials + dw EMA + cb.
__global__ __launch_bounds__(256)
void k_dwsum(const float* __restrict__ idxf, const float* __restrict__ zflat,
             const float* __restrict__ cb, const float* __restrict__ ema_dw,
             const float* __restrict__ smoothed, float* __restrict__ out_dw,
             float* __restrict__ out_cb, float* __restrict__ lossacc) {
    __shared__ int queue[1024];
    __shared__ int qn;
    __shared__ float lred[4];

    const int k = blockIdx.x;
    const int t = threadIdx.x;
    const float fk = (float)k;
    const float ck = cb[(size_t)k * D_DIM + t];

    float acc = 0.f;
    float ls  = 0.f;

    for (int chunk = 0; chunk < 64; ++chunk) {
        if (t == 0) qn = 0;
        __syncthreads();
#pragma unroll
        for (int j = 0; j < 4; ++j) {
            int n = chunk * 1024 + j * 256 + t;        // coalesced idx read
            if (idxf[n] == fk) {
                int p = atomicAdd(&qn, 1);
                queue[p] = n;
            }
        }
        __syncthreads();
        int m = qn;
        for (int i = 0; i < m; ++i) {
            int n = queue[i];
            float z = zflat[(size_t)n * D_DIM + t];    // coalesced row read
            acc += z;
            float df = ck - z;                         // same rounding as ref
            ls += df * df;
        }
    }

    size_t o = (size_t)k * D_DIM + t;
    float nd = fmaf(0.99f, ema_dw[o], 0.01f * acc);
    out_dw[o] = nd;
    out_cb[o] = nd / smoothed[k];

#pragma unroll
    for (int off = 32; off > 0; off >>= 1) ls += __shfl_down(ls, off, 64);
    if ((t & 63) == 0) lred[t >> 6] = ls;
    __syncthreads();
    if (t == 0) atomicAdd(lossacc, lred[0] + lred[1] + lred[2] + lred[3]);
}

// ---------------------------------------------------------------------------
// Straight-through z_q writer: pure float4 stream + L2 codebook gather.
// Also finalizes the loss (lossacc complete from k_dwsum, stream-ordered).
__global__ __launch_bounds__(256)
void k_zq(const float* __restrict__ ze, const float* __restrict__ cb,
          const float* __restrict__ idxf, float* __restrict__ out0,
          const float* __restrict__ lossacc, float* __restrict__ out_loss) {
    const int t = threadIdx.x;
    int g   = blockIdx.x * 64 + (t & 63);   // hw4-group id in [0, 16384)
    int b   = g >> 8;
    int hwl = (g & 255) * 4;
    int dg  = t >> 6;                        // d-quarter (0..3)
    const size_t base = (size_t)b * (D_DIM * HW_SZ) + hwl;

    int i0 = (int)idxf[b * HW_SZ + hwl + 0];
    int i1 = (int)idxf[b * HW_SZ + hwl + 1];
    int i2 = (int)idxf[b * HW_SZ + hwl + 2];
    int i3 = (int)idxf[b * HW_SZ + hwl + 3];
    const float* c0 = cb + (size_t)i0 * D_DIM;
    const float* c1 = cb + (size_t)i1 * D_DIM;
    const float* c2 = cb + (size_t)i2 * D_DIM;
    const float* c3 = cb + (size_t)i3 * D_DIM;

#pragma unroll 2
    for (int i = 0; i < 64; ++i) {
        int d = dg * 64 + i;
        size_t o = base + (size_t)d * HW_SZ;
        float4 z = *(const float4*)(ze + o);
        float4 r;
        r.x = z.x + (c0[d] - z.x);
        r.y = z.y + (c1[d] - z.y);
        r.z = z.z + (c2[d] - z.z);
        r.w = z.w + (c3[d] - z.w);
        *(float4*)(out0 + o) = r;
    }

    if (blockIdx.x == 0 && t == 0)
        out_loss[0] = 0.5f * lossacc[0] / ND_TOT;
}

// ---------------------------------------------------------------------------
extern "C" void kernel_launch(void* const* d_in, const int* in_sizes, int n_in,
                              void* d_out, int out_size, void* d_ws, size_t ws_size,
                              hipStream_t stream) {
    const float* ze     = (const float*)d_in[0];  // [64,256,32,32]
    const float* cb     = (const float*)d_in[1];  // [1024,256]
    const float* emacs  = (const float*)d_in[2];  // [1024]
    const float* emadw  = (const float*)d_in[3];  // [1024,256]
    float* out = (float*)d_out;
    float* ws  = (float*)d_ws;

    // Scratch choreography (stream-ordered reuse of d_out):
    //   CT (262144 fl) at out+0     : k_transpose -> k_argmin -> dead
    //   zflat (16.7M)  at out+0     : k_zt -> k_dwsum -> overwritten by k_zq
    //   ZN (65536)     at out+O_IDX : k_zn -> k_argmin (overwrites in-place)
    float* CT    = out;
    float* ZFLAT = out;
    float* ZN    = out + O_IDX;
    // d_ws scratch
    float* counts   = ws;                 // 1024
    float* lossacc  = ws + 1024;          // 1
    float* smoothed = ws + 1088;          // 1024
    float* CN       = ws + 2112;          // 1024

    hipMemsetAsync(ws, 0, 1025 * sizeof(float), stream);

    k_transpose<<<dim3(32, 8), 256, 0, stream>>>(cb, CT);
    k_cnorm<<<4, 256, 0, stream>>>(cb, CN);
    k_zn<<<256, 256, 0, stream>>>(ze, ZN);
    k_argmin<<<N_TOT / 128, 256, 0, stream>>>(ze, CT, CN, ZN, out + O_IDX, counts);
    k_zt<<<dim3(16, 4, 64), 256, 0, stream>>>(ze, ZFLAT);
    k_ema_cs<<<1, 1024, 0, stream>>>(emacs, counts, out + O_CS, smoothed);
    k_dwsum<<<K_CODES, 256, 0, stream>>>(out + O_IDX, ZFLAT, cb, emadw, smoothed,
                                         out + O_DW, out + O_CB, lossacc);
    k_zq<<<256, 256, 0, stream>>>(ze, cb, out + O_IDX, out + O_ZQ,
                                  lossacc, out + O_LOSS);
}

// Round 7
// 691.939 us; speedup vs baseline: 2.3513x; 1.0130x over previous
//
#include <hip/hip_runtime.h>
#include <math.h>

// Problem constants
#define K_CODES   1024
#define D_DIM     256
#define HW_SZ     1024          // 32*32
#define N_TOT     65536         // 64 * 1024
#define ND_TOT    16777216.0f   // N_TOT * D_DIM

// Output layout (float32, concatenated in reference return order)
#define O_ZQ    0
#define O_LOSS  16777216
#define O_IDX   16777217
#define O_CB    16842753
#define O_CS    17104897
#define O_DW    17105921

typedef float f2 __attribute__((ext_vector_type(2)));

// ---------------------------------------------------------------------------
// Transpose codebook [K][D] -> CT [D][K].  CT lives at the FRONT of the z_q
// output region (16B-aligned); consumed by k_argmin, then overwritten by k_zt.
__global__ void k_transpose(const float* __restrict__ cb, float* __restrict__ ct) {
    __shared__ float tile[32][33];
    int k0 = blockIdx.x * 32;
    int d0 = blockIdx.y * 32;
    int c = threadIdx.x & 31, r0 = threadIdx.x >> 5;
#pragma unroll
    for (int p = 0; p < 4; ++p) {
        int r = r0 + p * 8;
        tile[r][c] = cb[(k0 + r) * D_DIM + d0 + c];
    }
    __syncthreads();
#pragma unroll
    for (int p = 0; p < 4; ++p) {
        int r = r0 + p * 8;
        ct[(size_t)(d0 + r) * K_CODES + k0 + c] = tile[c][r];
    }
}

// ---------------------------------------------------------------------------
// Per-code squared norms, numpy-pairwise fp32 semantics (contract OFF).
__global__ void k_cnorm(const float* __restrict__ cb, float* __restrict__ cn) {
#pragma clang fp contract(off)
    int k = blockIdx.x * 256 + threadIdx.x;            // grid = 4 blocks
    const float* row = cb + (size_t)k * D_DIM;
    float s1 = 0.f, s2 = 0.f;
#pragma unroll
    for (int blk = 0; blk < 2; ++blk) {
        const float* p = row + blk * 128;
        float r[8];
#pragma unroll
        for (int j = 0; j < 8; ++j) { float v = p[j]; r[j] = v * v; }
        for (int i = 8; i < 128; i += 8) {
#pragma unroll
            for (int j = 0; j < 8; ++j) { float v = p[i + j]; r[j] = r[j] + v * v; }
        }
        float s = ((r[0] + r[1]) + (r[2] + r[3])) + ((r[4] + r[5]) + (r[6] + r[7]));
        if (blk == 0) s1 = s; else s2 = s;
    }
    cn[k] = s1 + s2;
}

// ---------------------------------------------------------------------------
// Per-row squared norms, numpy-pairwise fp32 semantics. Written into the
// O_IDX region; consumed by k_argmin, then overwritten by k_combine.
__global__ void k_zn(const float* __restrict__ ze, float* __restrict__ zn) {
#pragma clang fp contract(off)
    int n = blockIdx.x * 256 + threadIdx.x;            // grid = 256 blocks
    int b = n >> 10, hw = n & 1023;
    const float* p = ze + (size_t)b * (D_DIM * HW_SZ) + hw;
    float s1 = 0.f, s2 = 0.f;
#pragma unroll
    for (int blk = 0; blk < 2; ++blk) {
        const float* q = p + (size_t)(blk * 128) * HW_SZ;
        float r[8];
#pragma unroll
        for (int j = 0; j < 8; ++j) { float v = q[(size_t)j * HW_SZ]; r[j] = v * v; }
        for (int i = 8; i < 128; i += 8) {
#pragma unroll
            for (int j = 0; j < 8; ++j) {
                float v = q[(size_t)(i + j) * HW_SZ];
                r[j] = r[j] + v * v;
            }
        }
        float s = ((r[0] + r[1]) + (r[2] + r[3])) + ((r[4] + r[5]) + (r[6] + r[7]));
        if (blk == 0) s1 = s; else s2 = s;
    }
    zn[n] = s1 + s2;
}

// ---------------------------------------------------------------------------
// Argmin, k-split: grid = (512 n-tiles, 4 k-chunks). Scores bit-identical to
// the passing version: s = fl32(fl32(zn - 2*G) + cn), G = sequential fmaf
// over ascending d. Each block covers 128n x 256k, writes per-row partial
// (minval, minidx). 49.6 KB LDS -> 3 blocks/CU; 2048 blocks = 8 waves of
// blocks per CU for barrier/compute overlap.
__global__ __launch_bounds__(256, 3)
void k_argmin4(const float* __restrict__ ze, const float* __restrict__ ct,
               const float* __restrict__ cn, const float* __restrict__ znb,
               float* __restrict__ pval, int* __restrict__ pidx) {
    __shared__ __align__(16) float Zs[32][128];    // [d][n], rows contiguous
    __shared__ __align__(16) float Cs[32][260];    // [d][k], +4 pad per row

    const int t  = threadIdx.x;
    const int tx = t & 15;       // k-group (16 -> 16*16k = 256k)
    const int ty = t >> 4;       // n-group (16 -> 16*8n = 128n)
    const int kc = blockIdx.y;   // k-chunk (0..3)
    const int n0 = blockIdx.x * 128;
    const int b  = n0 >> 10;
    const int hw0 = n0 & 1023;
    const float* zb = ze + (size_t)b * (D_DIM * HW_SZ) + hw0;

    float znr[8];
#pragma unroll
    for (int j = 0; j < 8; ++j) znr[j] = znb[n0 + ty * 8 + j];

    float best[8];
    int   bidx[8];
#pragma unroll
    for (int j = 0; j < 8; ++j) { best[j] = INFINITY; bidx[j] = 0; }

    f2 acc2[8][8];
#pragma unroll
    for (int j = 0; j < 8; ++j)
#pragma unroll
        for (int i = 0; i < 8; ++i) acc2[j][i] = (f2)0.f;

    for (int dc = 0; dc < 8; ++dc) {
        __syncthreads();   // previous phase's LDS reads done before overwrite
        // stage Z: 32d x 128n via global_load_lds (wave-uniform base + lane*16)
#pragma unroll
        for (int r = 0; r < 4; ++r) {
            int idx4 = r * 256 + t;
            int dd = idx4 >> 5, nn4 = (idx4 & 31) * 4;
            const float* g = zb + (size_t)(dc * 32 + dd) * HW_SZ + nn4;
            char* l = (char*)&Zs[0][0] + (size_t)(r * 256 + (t & ~63)) * 16;
            __builtin_amdgcn_global_load_lds(
                (const __attribute__((address_space(1))) void*)g,
                (__attribute__((address_space(3))) void*)l, 16, 0, 0);
        }
        // stage C: 32d x 256k; each wave fills exactly one 256-float row,
        // so the +4 row pad is never crossed within an instruction.
#pragma unroll
        for (int r = 0; r < 8; ++r) {
            int idx4 = r * 256 + t;
            int dd = idx4 >> 6, kk4 = (idx4 & 63) * 4;
            const float* g = ct + (size_t)(dc * 32 + dd) * K_CODES + kc * 256 + kk4;
            char* l = (char*)&Cs[0][0] + (size_t)dd * (260 * 4);
            __builtin_amdgcn_global_load_lds(
                (const __attribute__((address_space(1))) void*)g,
                (__attribute__((address_space(3))) void*)l, 16, 0, 0);
        }
        __syncthreads();
#pragma unroll 2
        for (int d = 0; d < 32; ++d) {
            float4 za  = *(const float4*)&Zs[d][ty * 8];
            float4 zb4 = *(const float4*)&Zs[d][ty * 8 + 4];
            float4 ca  = *(const float4*)&Cs[d][tx * 4];
            float4 cb4 = *(const float4*)&Cs[d][64 + tx * 4];
            float4 cc4 = *(const float4*)&Cs[d][128 + tx * 4];
            float4 cd4 = *(const float4*)&Cs[d][192 + tx * 4];
            float zzs[8] = { za.x, za.y, za.z, za.w, zb4.x, zb4.y, zb4.z, zb4.w };
            f2 cc2[8] = { { ca.x,  ca.y  }, { ca.z,  ca.w  },
                          { cb4.x, cb4.y }, { cb4.z, cb4.w },
                          { cc4.x, cc4.y }, { cc4.z, cc4.w },
                          { cd4.x, cd4.y }, { cd4.z, cd4.w } };
#pragma unroll
            for (int j = 0; j < 8; ++j) {
                f2 zj = { zzs[j], zzs[j] };
#pragma unroll
                for (int i = 0; i < 8; ++i)
                    acc2[j][i] = __builtin_elementwise_fma(zj, cc2[i], acc2[j][i]);
            }
        }
    }
    // fold: s = fl32(fl32(zn - 2*acc) + cn); k ascending per thread
#pragma unroll
    for (int q = 0; q < 4; ++q)
#pragma unroll
        for (int l = 0; l < 4; ++l) {
            int k = kc * 256 + q * 64 + tx * 4 + l;
            float cnk = cn[k];
            int i2 = q * 2 + (l >> 1);
#pragma unroll
            for (int j = 0; j < 8; ++j) {
                float a = (l & 1) ? acc2[j][i2].y : acc2[j][i2].x;
                float tt = znr[j] - 2.0f * a;
                float s  = tt + cnk;
                if (s < best[j]) { best[j] = s; bidx[j] = k; }
            }
        }

    // cross-thread (tx) reduction via LDS reuse; lexicographic (v, idx)
    __syncthreads();
    float* rv = &Zs[0][0];          // 128*17 floats = 8704 B <= 16 KB
    int*   ri = (int*)&Cs[0][0];
#pragma unroll
    for (int j = 0; j < 8; ++j) {
        int n = ty * 8 + j;
        rv[n * 17 + tx] = best[j];
        ri[n * 17 + tx] = bidx[j];
    }
    __syncthreads();
    if (t < 128) {
        float bv = INFINITY; int bi = 0;
        for (int x = 0; x < 16; ++x) {
            float v = rv[t * 17 + x];
            int  id = ri[t * 17 + x];
            if (v < bv || (v == bv && id < bi)) { bv = v; bi = id; }
        }
        pval[kc * N_TOT + n0 + t] = bv;
        pidx[kc * N_TOT + n0 + t] = bi;
    }
}

// ---------------------------------------------------------------------------
// Combine the 4 k-chunk partials per row. Chunks ascend in k, so strict <
// preserves numpy first-index tie semantics. Fuses the counts histogram.
__global__ __launch_bounds__(256)
void k_combine(const float* __restrict__ pv, const int* __restrict__ pi,
               float* __restrict__ out_idx, float* __restrict__ counts) {
    int n = blockIdx.x * 256 + threadIdx.x;
    float bv = INFINITY; int bi = 0;
#pragma unroll
    for (int c = 0; c < 4; ++c) {
        float v = pv[c * N_TOT + n];
        int  id = pi[c * N_TOT + n];
        if (v < bv) { bv = v; bi = id; }
    }
    out_idx[n] = (float)bi;
    atomicAdd(counts + bi, 1.0f);
}

// ---------------------------------------------------------------------------
// Transpose z_e [64][256][1024] -> zflat [65536][256] (into O_ZQ region,
// overwriting the now-dead CT).
__global__ __launch_bounds__(256)
void k_zt(const float* __restrict__ ze, float* __restrict__ zflat) {
    __shared__ float tile[64][65];
    const int t = threadIdx.x;
    const int hw0 = blockIdx.x * 64;
    const int d0  = blockIdx.y * 64;
    const int b   = blockIdx.z;
    const size_t base_in = (size_t)b * (D_DIM * HW_SZ);
#pragma unroll
    for (int p = 0; p < 4; ++p) {
        int dd = p * 16 + (t >> 4);
        int c4 = (t & 15) * 4;
        float4 v = *(const float4*)(ze + base_in + (size_t)(d0 + dd) * HW_SZ + hw0 + c4);
        tile[dd][c4 + 0] = v.x;
        tile[dd][c4 + 1] = v.y;
        tile[dd][c4 + 2] = v.z;
        tile[dd][c4 + 3] = v.w;
    }
    __syncthreads();
#pragma unroll
    for (int p = 0; p < 4; ++p) {
        int hh  = p * 16 + (t >> 4);
        int dc4 = (t & 15) * 4;
        float4 v = { tile[dc4 + 0][hh], tile[dc4 + 1][hh],
                     tile[dc4 + 2][hh], tile[dc4 + 3][hh] };
        *(float4*)(zflat + (size_t)(b * HW_SZ + hw0 + hh) * D_DIM + d0 + dc4) = v;
    }
}

// ---------------------------------------------------------------------------
// EMA cluster size + smoothed (loss finalize lives in k_zq).
__global__ __launch_bounds__(1024)
void k_ema_cs(const float* __restrict__ ema_cs, const float* __restrict__ counts,
              float* __restrict__ out_cs, float* __restrict__ smoothed) {
    __shared__ float red[1024];
    int k = threadIdx.x;
    float cs_new = fmaf(0.99f, ema_cs[k], 0.01f * counts[k]);
    red[k] = cs_new;
    __syncthreads();
    for (int off = 512; off > 0; off >>= 1) {
        if (k < off) red[k] += red[k + off];
        __syncthreads();
    }
    float ntot = red[0];
    out_cs[k] = cs_new;
    smoothed[k] = (cs_new + 1e-5f) / (ntot + 0.01024f) * ntot;
}

// ---------------------------------------------------------------------------
// Per-code segment sum: one block per code; compact matching rows into an LDS
// queue (4096-chunks -> 4x fewer barriers than before), sum rows coalesced
// from zflat with 2-way load ILP. Fuses loss partials + dw EMA + cb write.
__global__ __launch_bounds__(256)
void k_dwsum(const float* __restrict__ idxf, const float* __restrict__ zflat,
             const float* __restrict__ cb, const float* __restrict__ ema_dw,
             const float* __restrict__ smoothed, float* __restrict__ out_dw,
             float* __restrict__ out_cb, float* __restrict__ lossacc) {
    __shared__ int queue[4096];
    __shared__ int qn;
    __shared__ float lred[4];

    const int k = blockIdx.x;
    const int t = threadIdx.x;
    const float fk = (float)k;
    const float ck = cb[(size_t)k * D_DIM + t];

    float acc = 0.f;
    float ls  = 0.f;

    for (int chunk = 0; chunk < 16; ++chunk) {
        if (t == 0) qn = 0;
        __syncthreads();
#pragma unroll
        for (int j = 0; j < 16; ++j) {
            int n = chunk * 4096 + j * 256 + t;        // coalesced idx read
            if (idxf[n] == fk) {
                int p = atomicAdd(&qn, 1);
                queue[p] = n;
            }
        }
        __syncthreads();
        int m = qn;
        int i = 0;
        for (; i + 1 < m; i += 2) {                    // 2-way load ILP
            int n1 = queue[i], n2 = queue[i + 1];
            float z1 = zflat[(size_t)n1 * D_DIM + t];
            float z2 = zflat[(size_t)n2 * D_DIM + t];
            acc += z1; float d1 = ck - z1; ls += d1 * d1;
            acc += z2; float d2 = ck - z2; ls += d2 * d2;
        }
        if (i < m) {
            int n1 = queue[i];
            float z1 = zflat[(size_t)n1 * D_DIM + t];
            acc += z1; float d1 = ck - z1; ls += d1 * d1;
        }
        __syncthreads();   // all queue reads done before next chunk's writes
    }

    size_t o = (size_t)k * D_DIM + t;
    float nd = fmaf(0.99f, ema_dw[o], 0.01f * acc);
    out_dw[o] = nd;
    out_cb[o] = nd / smoothed[k];

#pragma unroll
    for (int off = 32; off > 0; off >>= 1) ls += __shfl_down(ls, off, 64);
    if ((t & 63) == 0) lred[t >> 6] = ls;
    __syncthreads();
    if (t == 0) atomicAdd(lossacc, lred[0] + lred[1] + lred[2] + lred[3]);
}

// ---------------------------------------------------------------------------
// Straight-through z_q writer: pure float4 stream + L2 codebook gather.
// Also finalizes the loss (lossacc complete from k_dwsum, stream-ordered).
__global__ __launch_bounds__(256)
void k_zq(const float* __restrict__ ze, const float* __restrict__ cb,
          const float* __restrict__ idxf, float* __restrict__ out0,
          const float* __restrict__ lossacc, float* __restrict__ out_loss) {
    const int t = threadIdx.x;
    int g   = blockIdx.x * 64 + (t & 63);   // hw4-group id in [0, 16384)
    int b   = g >> 8;
    int hwl = (g & 255) * 4;
    int dg  = t >> 6;                        // d-quarter (0..3)
    const size_t base = (size_t)b * (D_DIM * HW_SZ) + hwl;

    int i0 = (int)idxf[b * HW_SZ + hwl + 0];
    int i1 = (int)idxf[b * HW_SZ + hwl + 1];
    int i2 = (int)idxf[b * HW_SZ + hwl + 2];
    int i3 = (int)idxf[b * HW_SZ + hwl + 3];
    const float* c0 = cb + (size_t)i0 * D_DIM;
    const float* c1 = cb + (size_t)i1 * D_DIM;
    const float* c2 = cb + (size_t)i2 * D_DIM;
    const float* c3 = cb + (size_t)i3 * D_DIM;

#pragma unroll 2
    for (int i = 0; i < 64; ++i) {
        int d = dg * 64 + i;
        size_t o = base + (size_t)d * HW_SZ;
        float4 z = *(const float4*)(ze + o);
        float4 r;
        r.x = z.x + (c0[d] - z.x);
        r.y = z.y + (c1[d] - z.y);
        r.z = z.z + (c2[d] - z.z);
        r.w = z.w + (c3[d] - z.w);
        *(float4*)(out0 + o) = r;
    }

    if (blockIdx.x == 0 && t == 0)
        out_loss[0] = 0.5f * lossacc[0] / ND_TOT;
}

// ---------------------------------------------------------------------------
extern "C" void kernel_launch(void* const* d_in, const int* in_sizes, int n_in,
                              void* d_out, int out_size, void* d_ws, size_t ws_size,
                              hipStream_t stream) {
    const float* ze     = (const float*)d_in[0];  // [64,256,32,32]
    const float* cb     = (const float*)d_in[1];  // [1024,256]
    const float* emacs  = (const float*)d_in[2];  // [1024]
    const float* emadw  = (const float*)d_in[3];  // [1024,256]
    float* out = (float*)d_out;
    float* ws  = (float*)d_ws;

    // Scratch choreography (stream-ordered reuse of d_out):
    //   CT (262144 fl)   at out+0     : k_transpose -> k_argmin4 -> dead
    //   zflat (16.7M)    at out+0     : k_zt -> k_dwsum -> overwritten by k_zq
    //   ZN (65536)       at out+O_IDX : k_zn -> k_argmin4 -> overwritten by
    //                                   k_combine's indices
    //   PV (262144 fl)   at out+O_CB  : k_argmin4 -> k_combine -> overwritten
    //                                   by k_dwsum's out_cb
    //   PI (262144 int)  at out+O_CS  : k_argmin4 -> k_combine -> overwritten
    //                                   by k_ema_cs (out_cs) + k_dwsum (out_dw)
    float* CT    = out;
    float* ZFLAT = out;
    float* ZN    = out + O_IDX;
    float* PV    = out + O_CB;
    int*   PI    = (int*)(out + O_CS);
    // d_ws scratch
    float* counts   = ws;                 // 1024
    float* lossacc  = ws + 1024;          // 1
    float* smoothed = ws + 1088;          // 1024
    float* CN       = ws + 2112;          // 1024

    hipMemsetAsync(ws, 0, 1025 * sizeof(float), stream);

    k_transpose<<<dim3(32, 8), 256, 0, stream>>>(cb, CT);
    k_cnorm<<<4, 256, 0, stream>>>(cb, CN);
    k_zn<<<256, 256, 0, stream>>>(ze, ZN);
    k_argmin4<<<dim3(512, 4), 256, 0, stream>>>(ze, CT, CN, ZN, PV, PI);
    k_combine<<<256, 256, 0, stream>>>(PV, PI, out + O_IDX, counts);
    k_zt<<<dim3(16, 4, 64), 256, 0, stream>>>(ze, ZFLAT);
    k_ema_cs<<<1, 1024, 0, stream>>>(emacs, counts, out + O_CS, smoothed);
    k_dwsum<<<K_CODES, 256, 0, stream>>>(out + O_IDX, ZFLAT, cb, emadw, smoothed,
                                         out + O_DW, out + O_CB, lossacc);
    k_zq<<<256, 256, 0, stream>>>(ze, cb, out + O_IDX, out + O_ZQ,
                                  lossacc, out + O_LOSS);
}